// Round 9
// baseline (157.756 us; speedup 1.0000x reference)
//
#include <hip/hip_runtime.h>
#include <hip/hip_bf16.h>

#define N_TOT 4096
#define D     512
#define BHALF 2048

// exp(2s) = 2^(s * 2*log2(e))
#define EXP2_SCALE 2.8853900817779268f
// exp(2*S_ii) for a normalized row (S_ii = 1 +- ~1e-2 in fp8; error in the
// final log is ~2e-5 -- negligible vs the 0.166 threshold)
#define E2 7.3890560989306495f

typedef __attribute__((ext_vector_type(4))) float floatx4;

// ---------------- kernel 1: normalize rows, cast to fp8 e4m3 --------------
// 1024 blocks x 256 threads; one 64-lane wave per row, no LDS, no barrier.
__global__ void normalize_kernel(const float* __restrict__ z_i,
                                 const float* __restrict__ z_j,
                                 unsigned char* __restrict__ zn) {
    const int wave = threadIdx.x >> 6, lane = threadIdx.x & 63;
    const int row = blockIdx.x * 4 + wave;
    const float* src = (row < BHALF) ? (z_i + (size_t)row * D)
                                     : (z_j + (size_t)(row - BHALF) * D);
    float4 v0 = ((const float4*)src)[lane];
    float4 v1 = ((const float4*)src)[lane + 64];
    float ss = v0.x*v0.x + v0.y*v0.y + v0.z*v0.z + v0.w*v0.w
             + v1.x*v1.x + v1.y*v1.y + v1.z*v1.z + v1.w*v1.w;
    #pragma unroll
    for (int off = 32; off > 0; off >>= 1) ss += __shfl_xor(ss, off);
    float inv = 1.0f / fmaxf(sqrtf(ss), 1e-8f);
    int w0 = __builtin_amdgcn_cvt_pk_fp8_f32(v0.x * inv, v0.y * inv, 0, false);
    w0     = __builtin_amdgcn_cvt_pk_fp8_f32(v0.z * inv, v0.w * inv, w0, true);
    int w1 = __builtin_amdgcn_cvt_pk_fp8_f32(v1.x * inv, v1.y * inv, 0, false);
    w1     = __builtin_amdgcn_cvt_pk_fp8_f32(v1.z * inv, v1.w * inv, w1, true);
    int* dst = (int*)(zn + (size_t)row * D);
    dst[lane]      = w0;
    dst[lane + 64] = w1;
}

// ---------------- kernel 2: full-S GEMM + exp + BLOCK-PRIVATE row sums ----
// Grid: 512 blocks = 32 row-strips x 16 col-chunks; block = 128 rows x 256
// cols of S (2 j-tiles), pure-register fp8 GEMM (R8 structure). Row partials
// accumulate in registers across both j-tiles and exit via PLAIN stores to
// rowsum_part[slot][row], slot = chunk*2 + wn. ZERO global atomics.
// R8 lesson: ~270K device-scope atomicAdds to 16 KB cost ~45 us (fabric RMW
// serialization on 8 non-coherent XCDs) -- they, not staging, were the
// bottleneck in every prior round. Full S costs 2x MFMA (6% busy = free).
// R4/R7 lesson: cross-block handoff only at kernel boundaries.
__launch_bounds__(256)
__global__ void gemm_fused(const unsigned char* __restrict__ zn,
                           float* __restrict__ rowsum_part,
                           float* __restrict__ spos) {
    const int s = blockIdx.x >> 4;               // row strip 0..31
    const int c = blockIdx.x & 15;               // col chunk 0..15
    const int i0 = s * 128;

    const int t = threadIdx.x;
    const int lane = t & 63, wave = t >> 6;
    const int wm = wave & 1, wn = wave >> 1;     // 2x2 waves -> 64x64 each
    const int quad = lane >> 4, l16 = lane & 15;

    // per-lane A fragment base (row i0+wm*64+l16, k-bytes quad*8 + kt*32)
    const unsigned char* pA = zn + (size_t)(i0 + wm*64 + l16) * D + quad*8;

    float rs[4][4];                              // row partials, both tiles
    #pragma unroll
    for (int tm = 0; tm < 4; ++tm)
        #pragma unroll
        for (int r = 0; r < 4; ++r) rs[tm][r] = 0.f;

    #pragma unroll
    for (int jt = 0; jt < 2; ++jt) {
        const int j0 = c * 256 + jt * 128;
        const unsigned char* pB = zn + (size_t)(j0 + wn*64 + l16) * D + quad*8;

        floatx4 acc[4][4] = {};
        long a0[4], b0[4], a1[4], b1[4];
        #pragma unroll
        for (int tm = 0; tm < 4; ++tm) a0[tm] = *(const long*)(pA + tm*16*D);
        #pragma unroll
        for (int tn = 0; tn < 4; ++tn) b0[tn] = *(const long*)(pB + tn*16*D);

        #pragma unroll
        for (int kt = 0; kt < 16; ++kt) {
            if (kt < 15) {                       // prefetch kt+1 fragments
                const int ko = (kt + 1) * 32;
                #pragma unroll
                for (int tm = 0; tm < 4; ++tm)
                    a1[tm] = *(const long*)(pA + tm*16*D + ko);
                #pragma unroll
                for (int tn = 0; tn < 4; ++tn)
                    b1[tn] = *(const long*)(pB + tn*16*D + ko);
            }
            #pragma unroll
            for (int tm = 0; tm < 4; ++tm)
                #pragma unroll
                for (int tn = 0; tn < 4; ++tn)
                    acc[tm][tn] = __builtin_amdgcn_mfma_f32_16x16x32_fp8_fp8(
                        a0[tm], b0[tn], acc[tm][tn], 0, 0, 0);
            #pragma unroll
            for (int i = 0; i < 4; ++i) { a0[i] = a1[i]; b0[i] = b1[i]; }
        }

        // accumulate exp(2s) into row partials (sum over this tile's cols)
        #pragma unroll
        for (int tm = 0; tm < 4; ++tm)
            #pragma unroll
            for (int tn = 0; tn < 4; ++tn)
                #pragma unroll
                for (int r = 0; r < 4; ++r)
                    rs[tm][r] += exp2f(acc[tm][tn][r] * EXP2_SCALE);

        // positive pairs: this strip's pos-tile is exactly j0 == i0^2048;
        // each row has a unique writer -> plain store.
        if (j0 == (i0 ^ BHALF)) {
            #pragma unroll
            for (int tm = 0; tm < 4; ++tm)
                #pragma unroll
                for (int tn = 0; tn < 4; ++tn)
                    #pragma unroll
                    for (int r = 0; r < 4; ++r) {
                        int li = wm*64 + tm*16 + quad*4 + r;
                        int lj = wn*64 + tn*16 + l16;
                        if (li == lj) spos[i0 + li] = acc[tm][tn][r];
                    }
        }
    }

    // reduce row partials over the 16 l16 lanes; lanes l16==0 store.
    const int slot = c * 2 + wn;                 // 0..31, unique per writer
    #pragma unroll
    for (int tm = 0; tm < 4; ++tm)
        #pragma unroll
        for (int r = 0; r < 4; ++r) {
            float v = rs[tm][r];
            v += __shfl_xor(v, 1);
            v += __shfl_xor(v, 2);
            v += __shfl_xor(v, 4);
            v += __shfl_xor(v, 8);
            if (l16 == 0) {
                int gi = i0 + wm*64 + tm*16 + quad*4 + r;
                rowsum_part[slot * N_TOT + gi] = v;   // plain store
            }
        }
}

// ---------------- kernel 3: final loss ----------------
// 1 block x 1024 threads; thread t handles rows t, t+1024, t+2048, t+3072.
// Reads of rowsum_part[slot][row] are coalesced across threads per slot.
__global__ void finalize_kernel(const float* __restrict__ rowsum_part,
                                const float* __restrict__ spos,
                                float* __restrict__ out) {
    int t = threadIdx.x;
    float acc = 0.f;
    #pragma unroll
    for (int rr = 0; rr < 4; ++rr) {
        int row = t + rr * 1024;
        float sum = 0.f;
        #pragma unroll
        for (int slot = 0; slot < 32; ++slot)
            sum += rowsum_part[slot * N_TOT + row];
        float sp = spos[row];
        float denom = sum - E2 + exp2f(sp * EXP2_SCALE);
        acc += __logf(denom) - 2.0f * sp;
    }
    #pragma unroll
    for (int off = 32; off > 0; off >>= 1) acc += __shfl_xor(acc, off);
    __shared__ float red[16];
    if ((t & 63) == 0) red[t >> 6] = acc;
    __syncthreads();
    if (t == 0) {
        float ssum = 0.f;
        #pragma unroll
        for (int w = 0; w < 16; ++w) ssum += red[w];
        out[0] = ssum / (float)N_TOT;
    }
}

extern "C" void kernel_launch(void* const* d_in, const int* in_sizes, int n_in,
                              void* d_out, int out_size, void* d_ws, size_t ws_size,
                              hipStream_t stream) {
    const float* z_i = (const float*)d_in[0];
    const float* z_j = (const float*)d_in[1];
    float* out = (float*)d_out;

    char* ws = (char*)d_ws;
    unsigned char* zn  = (unsigned char*)ws;                      // 2 MB
    float* rowsum_part = (float*)(ws + (size_t)N_TOT * D);        // 512 KB
    float* spos        = rowsum_part + 32 * N_TOT;                // 16 KB

    normalize_kernel<<<N_TOT / 4, 256, 0, stream>>>(z_i, z_j, zn);
    gemm_fused<<<512, 256, 0, stream>>>(zn, rowsum_part, spos);
    finalize_kernel<<<1, 1024, 0, stream>>>(rowsum_part, spos, out);
}

// Round 10
// 124.260 us; speedup vs baseline: 1.2696x; 1.2696x over previous
//
#include <hip/hip_runtime.h>
#include <hip/hip_bf16.h>

#define N_TOT 4096
#define D     512
#define BHALF 2048

// exp(2s) = 2^(s * 2*log2(e))
#define EXP2_SCALE 2.8853900817779268f
// exp(2*S_ii) for a normalized row (S_ii = 1 +- ~1e-2 in fp8; error in the
// final log is ~2e-5 -- negligible vs the 0.166 threshold)
#define E2 7.3890560989306495f

typedef __attribute__((ext_vector_type(4))) float floatx4;

#define AS_GLOBAL(p) ((const __attribute__((address_space(1))) void*)(p))
#define AS_LDS(p)    ((__attribute__((address_space(3))) void*)(p))

// s_waitcnt imm: vmcnt[3:0] | expcnt=7<<4 | lgkmcnt=15<<8 (ignore exp/lgkm)
#define WAITCNT_VM(n) (0xF70 | (n))

// ---------------- kernel 1: normalize rows, cast to fp8 e4m3 --------------
// 1024 blocks x 256 threads; one 64-lane wave per row, no LDS, no barrier.
__global__ void normalize_kernel(const float* __restrict__ z_i,
                                 const float* __restrict__ z_j,
                                 unsigned char* __restrict__ zn) {
    const int wave = threadIdx.x >> 6, lane = threadIdx.x & 63;
    const int row = blockIdx.x * 4 + wave;
    const float* src = (row < BHALF) ? (z_i + (size_t)row * D)
                                     : (z_j + (size_t)(row - BHALF) * D);
    float4 v0 = ((const float4*)src)[lane];
    float4 v1 = ((const float4*)src)[lane + 64];
    float ss = v0.x*v0.x + v0.y*v0.y + v0.z*v0.z + v0.w*v0.w
             + v1.x*v1.x + v1.y*v1.y + v1.z*v1.z + v1.w*v1.w;
    #pragma unroll
    for (int off = 32; off > 0; off >>= 1) ss += __shfl_xor(ss, off);
    float inv = 1.0f / fmaxf(sqrtf(ss), 1e-8f);
    int w0 = __builtin_amdgcn_cvt_pk_fp8_f32(v0.x * inv, v0.y * inv, 0, false);
    w0     = __builtin_amdgcn_cvt_pk_fp8_f32(v0.z * inv, v0.w * inv, w0, true);
    int w1 = __builtin_amdgcn_cvt_pk_fp8_f32(v1.x * inv, v1.y * inv, 0, false);
    w1     = __builtin_amdgcn_cvt_pk_fp8_f32(v1.z * inv, v1.w * inv, w1, true);
    int* dst = (int*)(zn + (size_t)row * D);
    dst[lane]      = w0;
    dst[lane + 64] = w1;
}

// ---- kernel 2: triangular GEMM + exp + block-private row/col partials ----
// 528 blocks of 256 threads; block -> (bi, bj), bj>=bi. fp8 e4m3 MFMA.
// Staging: COALESCED global_load_lds (R7: full 128-B lines, the only
// measured-coalesced path), triple-buffered, prefetch distance 2 (R6).
// Reduction: ZERO global atomics (R9 lesson: ~270K device atomicAdds cost
// ~15-17 us; R9 scattered register loads cost ~35 us/pass -- this round
// combines coalesced staging with atomic-free partials).
// Partial planes P=0..63 of rowsum_part[row][64]:
//   row-sums: block (bi,bj) wave wn -> plane 2*bj+wn (rows split by wm)
//   col-sums: block (bi,bj) wave wm -> plane 2*bi+wm (rows split by wn),
//             off-diagonal blocks only.
// This partitions every plane exactly (verified: a<=bj from row side,
// b>bi from col side, diagonal writes rows only) -- no init, no overlap.
__launch_bounds__(256)
__global__ void gemm_fused(const unsigned char* __restrict__ zn,
                           float* __restrict__ rowsum_part,
                           float* __restrict__ spos) {
    __shared__ unsigned char At[3][128 * 32];   // 4 KB per buffer
    __shared__ unsigned char Bt[3][128 * 32];

    // triangular decode (scalar, <=32 iters)
    int b = blockIdx.x, bi = 0, rowlen = 32;
    while (b >= rowlen) { b -= rowlen; rowlen--; bi++; }
    const int bj = bi + b;
    const int i0 = bi * 128;
    const int j0 = bj * 128;

    const int t = threadIdx.x;
    const int lane = t & 63, wave = t >> 6;
    const int wm = wave & 1, wn = wave >> 1;     // 2x2 waves -> 64x64 each
    const int quad = lane >> 4, l16 = lane & 15;

    // staging: per wave, 32 rows x 32 fp8 bytes = 1 KB = one 64x16B issue.
    const int srow = wave * 32 + (lane >> 1);
    const int scol = (lane & 1) * 16;
    const unsigned char* gA = zn + (size_t)(i0 + srow) * D + scol;
    const unsigned char* gB = zn + (size_t)(j0 + srow) * D + scol;
    const int lo = srow * 32 + scol;             // == wave*1024 + lane*16

    floatx4 acc[4][4] = {};

    // prologue: stage k-tiles 0 and 1 into buffers 0 and 1
    __builtin_amdgcn_global_load_lds(AS_GLOBAL(gA),      AS_LDS(&At[0][lo]), 16, 0, 0);
    __builtin_amdgcn_global_load_lds(AS_GLOBAL(gB),      AS_LDS(&Bt[0][lo]), 16, 0, 0);
    __builtin_amdgcn_global_load_lds(AS_GLOBAL(gA + 32), AS_LDS(&At[1][lo]), 16, 0, 0);
    __builtin_amdgcn_global_load_lds(AS_GLOBAL(gB + 32), AS_LDS(&Bt[1][lo]), 16, 0, 0);

    #pragma unroll
    for (int kt = 0; kt < 16; ++kt) {
        const int cur = kt % 3;
        // own tile-kt DMAs complete (2 newer pairs may stay in flight)
        if (kt < 15) __builtin_amdgcn_s_waitcnt(WAITCNT_VM(2));
        else         __builtin_amdgcn_s_waitcnt(WAITCNT_VM(0));
        __builtin_amdgcn_s_barrier();            // all waves' tile-kt done
        __asm__ volatile("" ::: "memory");       // no LDS-read hoisting
        if (kt < 14) {
            const int nxt = (kt + 2) % 3;
            const int ko = (kt + 2) * 32;
            __builtin_amdgcn_global_load_lds(AS_GLOBAL(gA + ko), AS_LDS(&At[nxt][lo]), 16, 0, 0);
            __builtin_amdgcn_global_load_lds(AS_GLOBAL(gB + ko), AS_LDS(&Bt[nxt][lo]), 16, 0, 0);
        }
        long af[4], bf[4];
        #pragma unroll
        for (int tm = 0; tm < 4; ++tm)
            af[tm] = *(const long*)(&At[cur][(wm*64 + tm*16 + l16) * 32 + quad*8]);
        #pragma unroll
        for (int tn = 0; tn < 4; ++tn)
            bf[tn] = *(const long*)(&Bt[cur][(wn*64 + tn*16 + l16) * 32 + quad*8]);
        #pragma unroll
        for (int tm = 0; tm < 4; ++tm)
            #pragma unroll
            for (int tn = 0; tn < 4; ++tn)
                acc[tm][tn] = __builtin_amdgcn_mfma_f32_16x16x32_fp8_fp8(
                    af[tm], bf[tn], acc[tm][tn], 0, 0, 0);
    }

    // epilogue: e = exp(2s); row partials + (off-diag) col partials,
    // all via plain stores to per-writer planes.
    float cs[4] = {0.f, 0.f, 0.f, 0.f};
    #pragma unroll
    for (int tm = 0; tm < 4; ++tm) {
        float rs[4] = {0.f, 0.f, 0.f, 0.f};
        #pragma unroll
        for (int tn = 0; tn < 4; ++tn)
            #pragma unroll
            for (int r = 0; r < 4; ++r) {
                float e = exp2f(acc[tm][tn][r] * EXP2_SCALE);
                rs[r] += e;
                cs[tn] += e;
            }
        #pragma unroll
        for (int r = 0; r < 4; ++r) {
            float v = rs[r];
            v += __shfl_xor(v, 1);
            v += __shfl_xor(v, 2);
            v += __shfl_xor(v, 4);
            v += __shfl_xor(v, 8);
            if (l16 == 0) {
                int gi = i0 + wm*64 + tm*16 + quad*4 + r;
                rowsum_part[(size_t)gi * 64 + 2*bj + wn] = v;
            }
        }
    }
    if (bi != bj) {
        #pragma unroll
        for (int tn = 0; tn < 4; ++tn) {
            float v = cs[tn];
            v += __shfl_xor(v, 16);
            v += __shfl_xor(v, 32);
            if (quad == 0) {
                int gj = j0 + wn*64 + tn*16 + l16;
                rowsum_part[(size_t)gj * 64 + 2*bi + wm] = v;
            }
        }
    }
    // positive pairs (j = i + 2048) live exactly in blocks bj == bi+16;
    // unique writer per row -> plain stores.
    if (bj == bi + 16) {
        #pragma unroll
        for (int tm = 0; tm < 4; ++tm)
            #pragma unroll
            for (int tn = 0; tn < 4; ++tn)
                #pragma unroll
                for (int r = 0; r < 4; ++r) {
                    int li = wm*64 + tm*16 + quad*4 + r;   // local row
                    int lj = wn*64 + tn*16 + l16;          // local col
                    if (li == lj) {
                        float s = acc[tm][tn][r];
                        spos[i0 + li]         = s;
                        spos[i0 + li + BHALF] = s;
                    }
                }
    }
}

// ---------------- kernel 3: final loss ----------------
// 1 block x 1024 threads; thread t handles rows t, t+1024, t+2048, t+3072.
// rowsum_part is [row][64] -> 16 float4 loads per row, fully vectorized.
__global__ void finalize_kernel(const float* __restrict__ rowsum_part,
                                const float* __restrict__ spos,
                                float* __restrict__ out) {
    int t = threadIdx.x;
    float acc = 0.f;
    #pragma unroll
    for (int rr = 0; rr < 4; ++rr) {
        int row = t + rr * 1024;
        const float4* p = (const float4*)(rowsum_part + (size_t)row * 64);
        float4 s4 = {0.f, 0.f, 0.f, 0.f};
        #pragma unroll
        for (int q = 0; q < 16; ++q) {
            float4 v = p[q];
            s4.x += v.x; s4.y += v.y; s4.z += v.z; s4.w += v.w;
        }
        float sum = (s4.x + s4.y) + (s4.z + s4.w);
        float sp = spos[row];
        float denom = sum - E2 + exp2f(sp * EXP2_SCALE);
        acc += __logf(denom) - 2.0f * sp;
    }
    #pragma unroll
    for (int off = 32; off > 0; off >>= 1) acc += __shfl_xor(acc, off);
    __shared__ float red[16];
    if ((t & 63) == 0) red[t >> 6] = acc;
    __syncthreads();
    if (t == 0) {
        float ssum = 0.f;
        #pragma unroll
        for (int w = 0; w < 16; ++w) ssum += red[w];
        out[0] = ssum / (float)N_TOT;
    }
}

extern "C" void kernel_launch(void* const* d_in, const int* in_sizes, int n_in,
                              void* d_out, int out_size, void* d_ws, size_t ws_size,
                              hipStream_t stream) {
    const float* z_i = (const float*)d_in[0];
    const float* z_j = (const float*)d_in[1];
    float* out = (float*)d_out;

    char* ws = (char*)d_ws;
    unsigned char* zn  = (unsigned char*)ws;                      // 2 MB
    float* rowsum_part = (float*)(ws + (size_t)N_TOT * D);        // 1 MB
    float* spos        = rowsum_part + (size_t)64 * N_TOT;        // 16 KB

    normalize_kernel<<<N_TOT / 4, 256, 0, stream>>>(z_i, z_j, zn);
    gemm_fused<<<(32 * 33) / 2, 256, 0, stream>>>(zn, rowsum_part, spos);
    finalize_kernel<<<1, 1024, 0, stream>>>(rowsum_part, spos, out);
}